// Round 2
// baseline (628.949 us; speedup 1.0000x reference)
//
#include <hip/hip_runtime.h>

typedef float floatx4 __attribute__((ext_vector_type(4)));  // clang-native for nontemporal builtins

// limiter per reference: idx1 & idx2 is provably always False
// (a*b<=0 and a*b>0 are disjoint), so w = min(|a+b|/2, 2*min(|a|,|b|)).
__device__ __forceinline__ float limiter_f(float a, float b) {
    float x1 = fabsf(a + b) * 0.5f;
    float x2 = 2.0f * fminf(fabsf(a), fabsf(b));
    return fminf(x1, x2);
}

__device__ __forceinline__ float rcp_fast(float x) {
    return __builtin_amdgcn_rcpf(x);   // v_rcp_f32, ~1 ulp
}

__device__ __forceinline__ void store_nt4(float* p, float a, float b, float c, float d) {
    floatx4 v = {a, b, c, d};
    __builtin_nontemporal_store(v, reinterpret_cast<floatx4*>(p));
}

// H = max( (A + B)/TAU_M, 0 )
//   A = exp(poly(T)),  T = max(VT - V, -1)/(SIGMA*sqrt2)
//   B/TAU_M = sqrt2 * max(dVdt/(SIGMA*sqrt2), 0) * SQRT_2_PI * exp(-T^2)/(1+erf(T))
//   sqrt2 * SQRT_2_PI = 2/sqrt(pi) = 1.1283791670955126
// erf via Abramowitz-Stegun 7.1.26 (|err| <= 1.5e-7), reusing E = exp(-T^2).
__device__ __forceinline__ float h_func(float V, float dVdt) {
    const float INV_S_SQRT2 = 0.23570226039551584f;  // 1/(SIGMA*sqrt(2)), SIGMA=3
    float dV = fmaxf(-55.0f - V, -1.0f);
    float T  = dV * INV_S_SQRT2;
    float T2 = T * T;
    float poly = 0.0061f + T * (-1.12f + T * (-0.257f + T * (-0.072f + T * (-0.0117f))));
    float A = __expf(poly);
    float E = __expf(-T2);
    // erf(|T|) = 1 - (a1 t + ... + a5 t^5) * exp(-T^2),  t = 1/(1 + p|T|)
    float t = rcp_fast(fmaf(0.3275911f, fabsf(T), 1.0f));
    float q = t * (0.254829592f +
              t * (-0.284496736f +
              t * (1.421413741f +
              t * (-1.453152027f +
              t * 1.061405429f))));
    float erfT = copysignf(1.0f - q * E, T);
    float r = fmaxf(INV_S_SQRT2 * dVdt, 0.0f);               // = -dT_dt
    float F = E * rcp_fast(1.00000001f + erfT);
    return fmaxf(fmaf(0.1f, A, 1.1283791670955126f * F * r), 0.0f);
}

__global__ __launch_bounds__(256) void neuron_kernel(
    const float* __restrict__ z, const float* __restrict__ S,
    const float* __restrict__ V, const float* __restrict__ dVdt,
    float* __restrict__ out, int n)
{
    int i0 = (blockIdx.x * blockDim.x + threadIdx.x) * 8;
    if (i0 >= n) return;

    const float4 za = *reinterpret_cast<const float4*>(z + i0);
    const float4 zb = *reinterpret_cast<const float4*>(z + i0 + 4);
    const float4 sa = *reinterpret_cast<const float4*>(S + i0);
    const float4 sb = *reinterpret_cast<const float4*>(S + i0 + 4);
    const float4 va = *reinterpret_cast<const float4*>(V + i0);
    const float4 vb = *reinterpret_cast<const float4*>(V + i0 + 4);
    const float4 ga = *reinterpret_cast<const float4*>(dVdt + i0);
    const float4 gb = *reinterpret_cast<const float4*>(dVdt + i0 + 4);

    // halo: z[i0-2], z[i0-1] (8B-aligned since i0 % 8 == 0), z[i0+8]
    float zm2 = 0.0f, zm1 = 0.0f;
    if (i0 >= 2) {
        const float2 t2 = *reinterpret_cast<const float2*>(z + i0 - 2);
        zm2 = t2.x; zm1 = t2.y;
    }
    float zp8 = (i0 + 8 < n) ? z[i0 + 8] : 0.0f;

    // lz[k] = z[i0-2+k], ld[j] = z[i0-1+j] - z[i0-2+j]
    float lz[11] = {zm2, zm1, za.x, za.y, za.z, za.w, zb.x, zb.y, zb.z, zb.w, zp8};
    float ld[10];
#pragma unroll
    for (int j = 0; j < 10; ++j) ld[j] = lz[j + 1] - lz[j];

    // w[j] = limiter(ld[j+1], ld[j]); element t uses wi = w[t+1], wim1 = w[t]
    // (adjacent elements share one limiter: 9 limiters per 8 elements, not 16)
    float w[9];
#pragma unroll
    for (int j = 0; j < 9; ++j) w[j] = limiter_f(ld[j + 1], ld[j]);

    const float sv[8] = {sa.x, sa.y, sa.z, sa.w, sb.x, sb.y, sb.z, sb.w};
    float dz[8];
#pragma unroll
    for (int t = 0; t < 8; ++t) {
        // -2*(dm1 + 0.4*(wi - wim1)) - s  ==  fma(-2, dm1, fma(-0.8, dw, -s))
        dz[t] = fmaf(-2.0f, ld[t + 1], fmaf(-0.8f, w[t + 1] - w[t], -sv[t]));
    }
    if (i0 == 0) {                       // elements i=0 and i=1
        dz[0] = -2.0f * lz[2] - sv[0];                       // -z[0]/DTS - S[0]
        dz[1] = fmaf(-2.0f, ld[2], fmaf(-0.8f, w[2], -sv[1]));  // wi_1[0] = 0
    }
    if (i0 + 8 == n) {                   // element i = n-1
        dz[7] = fmaf(2.0f, lz[8], fmaf(0.8f, w[7], -sv[7])); // z[n-2] + coef*wi[-1]
    }

    // outputs are never re-read: nontemporal stores keep inputs resident in LLC
    store_nt4(out + i0,     dz[0], dz[1], dz[2], dz[3]);
    store_nt4(out + i0 + 4, dz[4], dz[5], dz[6], dz[7]);

    store_nt4(out + n + i0,
              h_func(va.x, ga.x), h_func(va.y, ga.y),
              h_func(va.z, ga.z), h_func(va.w, ga.w));
    store_nt4(out + n + i0 + 4,
              h_func(vb.x, gb.x), h_func(vb.y, gb.y),
              h_func(vb.z, gb.z), h_func(vb.w, gb.w));
}

extern "C" void kernel_launch(void* const* d_in, const int* in_sizes, int n_in,
                              void* d_out, int out_size, void* d_ws, size_t ws_size,
                              hipStream_t stream) {
    const float* z    = (const float*)d_in[0];
    const float* S    = (const float*)d_in[1];
    const float* V    = (const float*)d_in[2];
    const float* dVdt = (const float*)d_in[3];
    float* out = (float*)d_out;
    const int n = in_sizes[0];

    const int threads = 256;
    const int blocks = (n / 8 + threads - 1) / threads;
    neuron_kernel<<<blocks, threads, 0, stream>>>(z, S, V, dVdt, out, n);
}